// Round 1
// baseline (440.884 us; speedup 1.0000x reference)
//
#include <hip/hip_runtime.h>
#include <math.h>

// Problem constants (fixed by setup_inputs)
#define NB 8
#define NC 256
#define NH 128
#define NW 128
#define HW (NH*NW)        // 16384
#define NP 64
#define NK 2
#define CK 8              // C-chunk per register buffer

// Workspace float layout
#define WS_CENTERS 0                     // NP*NC scaled centers, [P][C]
#define WS_PSQ     (NP*NC)               // NP
#define WS_U       (NP*NC + NP)          // NP*NK
#define WS_AL      (NP*NC + NP + NP*NK)  // NP
#define WS_G2      (NP*NC + 2*NP + NP*NK)// NP
#define WS_TOTAL   (NP*NC + 3*NP + NP*NK)

__global__ __launch_bounds__(64) void geo_precompute(
    const float* __restrict__ cm,        // (P,K)
    const float* __restrict__ alpha,     // (P,1)
    const float* __restrict__ gamma_,    // (P,1)
    const float* __restrict__ centers,   // (P,C)
    const float* __restrict__ geo,       // (P,1)
    float* __restrict__ ws)
{
    const int p = threadIdx.x;
    if (p >= NP) return;
    // scale = 1 + 0.1*tanh(mean(geo_constraints)); redundantly per thread (cheap)
    float s = 0.f;
    #pragma unroll
    for (int i = 0; i < NP; ++i) s += geo[i];
    const float scale = 1.0f + 0.1f * tanhf(s * (1.0f / NP));

    float psq = 0.f;
    for (int c = 0; c < NC; ++c) {
        float v = centers[p*NC + c] * scale;
        ws[WS_CENTERS + p*NC + c] = v;
        psq += v * v;
    }
    ws[WS_PSQ + p] = psq;

    float b0 = cm[p*NK+0]; b0 *= b0;
    float b1 = cm[p*NK+1]; b1 *= b1;
    const float bs = b0 + b1;
    ws[WS_U + p*NK+0] = b0 / bs;
    ws[WS_U + p*NK+1] = b1 / bs;
    ws[WS_AL + p] = 0.99f / (1.0f + expf(-alpha[p]));
    ws[WS_G2 + p] = gamma_[p] * gamma_[p];
}

__global__ __launch_bounds__(256) void geo_main(
    const float* __restrict__ feats,     // (B,C,H,W)
    const float* __restrict__ ws,
    float* __restrict__ out)             // (B,3,H,W)
{
    __shared__ float sC[NP*NC];          // 64 KiB, [P][C] layout
    __shared__ float sPsq[NP];
    __shared__ float sU[NP*NK];
    __shared__ float sAl[NP];
    __shared__ float sG2[NP];

    const int tid = threadIdx.x;

    // Cooperative stage of scaled centers into LDS (float4)
    #pragma unroll
    for (int i = tid*4; i < NP*NC; i += 256*4) {
        *(float4*)&sC[i] = *(const float4*)&ws[WS_CENTERS + i];
    }
    if (tid < NP) {
        sPsq[tid] = ws[WS_PSQ + tid];
        sAl[tid]  = ws[WS_AL + tid];
        sG2[tid]  = ws[WS_G2 + tid];
    }
    if (tid < NP*NK) sU[tid] = ws[WS_U + tid];
    __syncthreads();

    const int pix = blockIdx.x * 256 + tid;     // 0 .. B*HW-1 (exact grid)
    const int b  = pix >> 14;                   // / HW
    const int hw = pix & (HW - 1);
    const float* __restrict__ fp = feats + (size_t)b * NC * HW + hw;

    float acc[NP];
    #pragma unroll
    for (int p = 0; p < NP; ++p) acc[p] = 0.f;
    float xsq = 0.f;

    float fA[CK], fB[CK];

    // prologue: load chunk 0
    #pragma unroll
    for (int cc = 0; cc < CK; ++cc) fA[cc] = fp[(cc) * HW];

    // 32 chunks of CK=8, processed 2 per iteration with register double-buffer
    #pragma unroll 1
    for (int ci = 0; ci < NC/(2*CK); ++ci) {
        const int c0 = ci * (2*CK);

        // prefetch chunk c0+CK into fB
        #pragma unroll
        for (int cc = 0; cc < CK; ++cc) fB[cc] = fp[(c0 + CK + cc) * HW];

        // compute on fA @ c0
        #pragma unroll
        for (int cc = 0; cc < CK; ++cc) xsq += fA[cc] * fA[cc];
        #pragma unroll
        for (int p = 0; p < NP; ++p) {
            #pragma unroll
            for (int cc = 0; cc < CK; ++cc)
                acc[p] += fA[cc] * sC[p*NC + c0 + cc];
        }

        // prefetch chunk c0+2*CK into fA (skip on last iteration)
        if (ci != NC/(2*CK) - 1) {
            #pragma unroll
            for (int cc = 0; cc < CK; ++cc) fA[cc] = fp[(c0 + 2*CK + cc) * HW];
        }

        // compute on fB @ c0+CK
        #pragma unroll
        for (int cc = 0; cc < CK; ++cc) xsq += fB[cc] * fB[cc];
        #pragma unroll
        for (int p = 0; p < NP; ++p) {
            #pragma unroll
            for (int cc = 0; cc < CK; ++cc)
                acc[p] += fB[cc] * sC[p*NC + c0 + CK + cc];
        }
    }

    // Per-pixel sequential scan over prototypes (all in registers)
    float ms0 = 0.f, ms1 = 0.f, mt = 1.f;
    #pragma unroll
    for (int p = 0; p < NP; ++p) {
        const float d = 0.5f * (xsq - 2.f * acc[p] + sPsq[p]);
        const float sact = sAl[p] * expf(-sG2[p] * d);
        const float mth = 1.f - sact;
        const float m0 = sact * sU[2*p+0];
        const float m1 = sact * sU[2*p+1];
        ms0 = ms0 * (m0 + mth) + m0 * mt;
        ms1 = ms1 * (m1 + mth) + m1 * mt;
        mt *= mth;
    }

    const float inv = 1.f / (ms0 + ms1 + mt + 1e-12f);
    float* __restrict__ op = out + (size_t)b * 3 * HW + hw;
    op[0*HW] = ms0 * inv;
    op[1*HW] = ms1 * inv;
    op[2*HW] = mt  * inv;
}

extern "C" void kernel_launch(void* const* d_in, const int* in_sizes, int n_in,
                              void* d_out, int out_size, void* d_ws, size_t ws_size,
                              hipStream_t stream) {
    const float* feats   = (const float*)d_in[0];
    // d_in[1] = geo_context (unused by reference)
    const float* cm      = (const float*)d_in[2];
    const float* alpha   = (const float*)d_in[3];
    const float* gamma_  = (const float*)d_in[4];
    const float* centers = (const float*)d_in[5];
    const float* geo     = (const float*)d_in[6];
    float* out = (float*)d_out;
    float* ws  = (float*)d_ws;

    geo_precompute<<<1, 64, 0, stream>>>(cm, alpha, gamma_, centers, geo, ws);

    const int total = NB * HW;                 // 131072
    geo_main<<<total / 256, 256, 0, stream>>>(feats, ws, out);
}